// Round 13
// baseline (122.520 us; speedup 1.0000x reference)
//
#include <hip/hip_runtime.h>
#include <stdint.h>

#define HH 2048
#define WW 2048
#define NPIX (HH*WW)
#define MROW (WW/32)      // 64 mask words per row
#define TSX 64
#define TSY 32
#define NBLK ((WW/TSX)*(HH/TSY))   // 2048 contour blocks

// DIAGNOSTIC ROUND: A body x8, B body x12 (idempotent reps; memory clobber
// stops load hoisting) so both dispatches exceed the ~48us harness fills and
// surface in the rocprof top-5 with VALUBusy/Occupancy/FETCH. Revert next round.

// ---------------- Kernel A: fw nibble plane + bit-packed combined mask ----------------
__global__ __launch_bounds__(256) void fw_kernel(
    const float* __restrict__ target, uint16_t* __restrict__ fwnib,
    uint32_t* __restrict__ mask)
{
    __shared__ uint8_t nib[256];
    const int t = threadIdx.x;
    const int i = blockIdx.x * 256 + t;   // quad index, grid sized exactly
    const float4* t4 = (const float4*)target;
    #pragma unroll 1
    for (int rep = 0; rep < 8; ++rep) {
        asm volatile("" ::: "memory");    // force real re-loads each rep
        __syncthreads();                  // protect nib[] reuse across reps
        float4 a = t4[i];
        float4 b = t4[(NPIX/4) + i];
        float4 c = t4[2*(NPIX/4) + i];
        float4 d = t4[3*(NPIX/4) + i];
        float4 e = t4[4*(NPIX/4) + i];
        uint32_t f0 = (uint32_t)(a.x + b.x + c.x + d.x + e.x);
        uint32_t f1 = (uint32_t)(a.y + b.y + c.y + d.y + e.y);
        uint32_t f2 = (uint32_t)(a.z + b.z + c.z + d.z + e.z);
        uint32_t f3 = (uint32_t)(a.w + b.w + c.w + d.w + e.w);
        fwnib[i] = (uint16_t)(f0 | (f1 << 4) | (f2 << 8) | (f3 << 12));
        nib[t] = (uint8_t)((f0 ? 1u : 0u) | (f1 ? 2u : 0u) | (f2 ? 4u : 0u) | (f3 ? 8u : 0u));
        __syncthreads();
        if (t < 32) {
            const uint8_t* p = nib + t * 8;
            uint32_t w = 0;
            #pragma unroll
            for (int k = 0; k < 8; ++k) w |= (uint32_t)p[k] << (4 * k);
            mask[blockIdx.x * 32 + t] = w;
        }
    }
}

// ---------------- Kernel B: contour -> byte code, per-block min/max ----------------
// Round-12 body (bit-exact), run x12 for diagnosis.
__global__ __launch_bounds__(256) void contour_kernel(
    const uint16_t* __restrict__ fwnib, const uint32_t* __restrict__ mask,
    const float* __restrict__ dk,
    uint8_t* __restrict__ wcode, float* __restrict__ pmin, float* __restrict__ pmax)
{
    __shared__ uint32_t maskw[TSY + 8][4];  // 40 halo rows x 128 bits (gx0-32..gx0+95)
    __shared__ uint8_t  lutm2[512];         // 9-bit diff-mask -> min|dx|^2 (8 -> 64)
    __shared__ float    inv_ext[65];        // d^2 -> 1/dist, 0 if unachievable/none(64)
    __shared__ float    redmn[4], redmx[4];

    const int t   = threadIdx.x;
    const int gx0 = blockIdx.x * TSX;
    const int gy0 = blockIdx.y * TSY;
    const int rl  = t >> 3;                 // tile row 0..31
    const int xg  = t & 7;                  // 8-px group in row
    const int gy  = gy0 + rl;
    const int gxb = gx0 + 8 * xg;
    const int w0  = gx0 >> 5;

    #pragma unroll 1
    for (int rep = 0; rep < 12; ++rep) {
        asm volatile("" ::: "memory");      // force real re-loads each rep
        __syncthreads();                    // protect LDS reuse across reps

        if (t < (TSY + 8) * 4) {            // 160 halo words, one per thread
            int hr = t >> 2, wc = t & 3;
            int hgy = gy0 - 4 + hr; hgy = min(max(hgy, 0), HH - 1);
            const uint32_t* rowp = mask + hgy * MROW;
            int wi = w0 - 1 + wc;
            uint32_t v;
            if (wi < 0)            v = (rowp[0] & 1u) ? 0xFFFFFFFFu : 0u;
            else if (wi > MROW-1)  v = (rowp[MROW-1] >> 31) ? 0xFFFFFFFFu : 0u;
            else                   v = rowp[wi];
            maskw[hr][wc] = v;
        }
        const uint32_t fwd = *(const uint32_t*)((const uint8_t*)fwnib + gy * (WW/2) + (gxb >> 1));
        for (int idx = t; idx < 512; idx += 256) {   // min|dx|^2 LUT
            uint32_t rev = __builtin_bitreverse32((uint32_t)idx) >> 23;
            uint32_t g = ((((uint32_t)idx | rev) >> 4) & 0x1Fu) | 0x100u;
            uint32_t mk = (uint32_t)__builtin_ctz(g);
            lutm2[idx] = (uint8_t)(mk * mk);
        }
        if (t < 65) inv_ext[t] = 0.0f;
        __syncthreads();
        if (t < 81) {
            int iy = t / 9, jx = t - (t / 9) * 9;
            int dy = iy - 4, dx = jx - 4;
            int d2 = dy * dy + dx * dx;
            if (d2 != 0) inv_ext[d2] = 1.0f / (dk[t] / (1.0f + 1e-10f) + 1e-10f);
        }
        __syncthreads();

        const int pos  = 8 * xg + 28;
        const int wsel = pos >> 5;
        const uint32_t sh = (uint32_t)(pos & 31);
        uint32_t wrow[9];
        #pragma unroll
        for (int k = 0; k < 9; ++k) {
            uint64_t v = (((uint64_t)maskw[rl + k][wsel + 1]) << 32) | maskw[rl + k][wsel];
            wrow[k] = (uint32_t)(v >> sh);
        }
        uint32_t orx[4], andx[4];
        #pragma unroll
        for (int k = 1; k <= 4; ++k) {
            orx[k-1]  = wrow[4 - k] | wrow[4 + k];
            andx[k-1] = wrow[4 - k] & wrow[4 + k];
        }
        float lmn = __int_as_float(0x7F800000);
        float lmx = 0.0f;
        uint32_t outb0 = 0, outb1 = 0;
        #pragma unroll
        for (int j = 0; j < 8; ++j) {
            uint32_t craw = (wrow[4] >> (4 + j)) & 1u;
            uint32_t cm = 0u - craw;
            uint32_t x0 = ((wrow[4] ^ cm) >> j) & 0x1FFu;
            uint32_t d2m = (uint32_t)lutm2[x0];
            #pragma unroll
            for (int k = 1; k <= 4; ++k) {
                uint32_t sel = craw ? andx[k-1] : orx[k-1];
                uint32_t x = ((sel ^ cm) >> j) & 0x1FFu;
                uint32_t d2 = (uint32_t)lutm2[x] + (uint32_t)(k * k);
                d2m = min(d2m, d2);
            }
            float contour = inv_ext[d2m];
            uint32_t enc = (d2m > 32u) ? 26u : d2m;
            uint32_t fwj = (fwd >> (4 * j)) & 0xFu;
            uint32_t code = ((enc - 1u) << 3) | fwj;
            if (j < 4) outb0 |= code << (8 * j);
            else       outb1 |= code << (8 * (j - 4));
            float wv = (float)fwj + contour;
            wv = wv * wv;
            lmn = fminf(lmn, wv);
            lmx = fmaxf(lmx, wv);
        }
        uint2 ob; ob.x = outb0; ob.y = outb1;
        *(uint2*)(wcode + gy * WW + gxb) = ob;

        #pragma unroll
        for (int off = 32; off > 0; off >>= 1) {
            lmn = fminf(lmn, __shfl_xor(lmn, off));
            lmx = fmaxf(lmx, __shfl_xor(lmx, off));
        }
        if ((t & 63) == 0) { redmn[t >> 6] = lmn; redmx[t >> 6] = lmx; }
        __syncthreads();
        if (t == 0) {
            float mn = fminf(fminf(redmn[0], redmn[1]), fminf(redmn[2], redmn[3]));
            float mx = fmaxf(fmaxf(redmx[0], redmx[1]), fmaxf(redmx[2], redmx[3]));
            int bid = blockIdx.y * gridDim.x + blockIdx.x;
            pmin[bid] = mn;
            pmax[bid] = mx;
        }
    }
}

// ---------------- Kernel C: redundant partial-reduce + LUT decode + normalize ----------------
__global__ __launch_bounds__(256) void norm_kernel(
    const uint8_t* __restrict__ wcode, const float* __restrict__ dk,
    const float* __restrict__ pmin, const float* __restrict__ pmax,
    float* __restrict__ out)
{
    __shared__ float ct[33];       // d^2 -> 1/dist (0 where none, incl code 26)
    __shared__ float wlut[256];    // code byte -> w value
    __shared__ float smn[4], smx[4];
    const int t = threadIdx.x;

    if (t < 33) ct[t] = 0.0f;
    const float4* pn4 = (const float4*)pmin;
    const float4* px4 = (const float4*)pmax;
    float4 a = pn4[t * 2], b = pn4[t * 2 + 1];
    float4 c = px4[t * 2], d = px4[t * 2 + 1];
    __syncthreads();
    if (t < 81) {
        int iy = t / 9, jx = t - (t / 9) * 9;
        int dy = iy - 4, dx = jx - 4;
        int d2 = dy * dy + dx * dx;
        if (d2 != 0) ct[d2] = 1.0f / (dk[t] / (1.0f + 1e-10f) + 1e-10f);
    }
    __syncthreads();
    {
        float wv = (float)(t & 7) + ct[(t >> 3) + 1];
        wlut[t] = wv * wv;
    }
    float mn = fminf(fminf(fminf(a.x, a.y), fminf(a.z, a.w)),
                     fminf(fminf(b.x, b.y), fminf(b.z, b.w)));
    float mx = fmaxf(fmaxf(fmaxf(c.x, c.y), fmaxf(c.z, c.w)),
                     fmaxf(fmaxf(d.x, d.y), fmaxf(d.z, d.w)));
    #pragma unroll
    for (int off = 32; off > 0; off >>= 1) {
        mn = fminf(mn, __shfl_xor(mn, off));
        mx = fmaxf(mx, __shfl_xor(mx, off));
    }
    if ((t & 63) == 0) { smn[t >> 6] = mn; smx[t >> 6] = mx; }
    __syncthreads();
    mn = fminf(fminf(smn[0], smn[1]), fminf(smn[2], smn[3]));
    mx = fmaxf(fmaxf(smx[0], smx[1]), fmaxf(smx[2], smx[3]));
    const float rden = 1.0f / (mx - mn + 1e-10f);

    const int i = blockIdx.x * 256 + t;          // 8-px group id
    uint2 cb = ((const uint2*)wcode)[i];
    uint32_t b0 = cb.x, b1 = cb.y;
    float4 o0, o1;
    o0.x = (b0 & 7u)         ? (wlut[b0 & 0xFFu] - mn) * rden         : 0.0f;
    o0.y = ((b0 >> 8) & 7u)  ? (wlut[(b0 >> 8) & 0xFFu] - mn) * rden  : 0.0f;
    o0.z = ((b0 >> 16) & 7u) ? (wlut[(b0 >> 16) & 0xFFu] - mn) * rden : 0.0f;
    o0.w = ((b0 >> 24) & 7u) ? (wlut[b0 >> 24] - mn) * rden           : 0.0f;
    o1.x = (b1 & 7u)         ? (wlut[b1 & 0xFFu] - mn) * rden         : 0.0f;
    o1.y = ((b1 >> 8) & 7u)  ? (wlut[(b1 >> 8) & 0xFFu] - mn) * rden  : 0.0f;
    o1.z = ((b1 >> 16) & 7u) ? (wlut[(b1 >> 16) & 0xFFu] - mn) * rden : 0.0f;
    o1.w = ((b1 >> 24) & 7u) ? (wlut[b1 >> 24] - mn) * rden           : 0.0f;
    ((float4*)out)[i * 2]     = o0;
    ((float4*)out)[i * 2 + 1] = o1;
}

extern "C" void kernel_launch(void* const* d_in, const int* in_sizes, int n_in,
                              void* d_out, int out_size, void* d_ws, size_t ws_size,
                              hipStream_t stream)
{
    const float* target = (const float*)d_in[0];
    const float* dk     = (const float*)d_in[1];
    float* out = (float*)d_out;

    uint8_t* wsb = (uint8_t*)d_ws;
    uint16_t* fwnib = (uint16_t*)wsb;                        // 2 MB fw nibble plane
    uint8_t*  wcode = wsb + NPIX/2;                          // 4 MB u8 code plane
    uint32_t* mask  = (uint32_t*)(wsb + NPIX/2 + NPIX);      // 512 KB packed mask
    float*    pmin  = (float*)(wsb + NPIX/2 + NPIX + NPIX/8);// 8 KB partial mins
    float*    pmax  = pmin + NBLK;                           // 8 KB partial maxs

    fw_kernel<<<NPIX / 4 / 256, 256, 0, stream>>>(target, fwnib, mask);

    dim3 gridB(WW / TSX, HH / TSY);
    contour_kernel<<<gridB, 256, 0, stream>>>(fwnib, mask, dk, wcode, pmin, pmax);

    norm_kernel<<<NPIX / 8 / 256, 256, 0, stream>>>(wcode, dk, pmin, pmax, out);
}

// Round 14
// 35.326 us; speedup vs baseline: 3.4682x; 3.4682x over previous
//
#include <hip/hip_runtime.h>
#include <stdint.h>

#define HH 2048
#define WW 2048
#define NPIX (HH*WW)
#define MROW (WW/32)      // 64 mask words per row
#define TSX 64
#define TSY 32
#define NBLK ((WW/TSX)*(HH/TSY))   // 2048 contour blocks

// min|dx|^2 from 9-bit diff mask (center bit 4): pure ALU, returns 64 if none
__device__ __forceinline__ uint32_t m2gadget(uint32_t x) {
    uint32_t rev = __builtin_bitreverse32(x) >> 23;               // dx -> -dx
    uint32_t g = (((x | rev) >> 4) & 0x1Fu) | 0x100u;             // |dx| presence + sentinel
    uint32_t mk = (uint32_t)__builtin_ctz(g);                     // min |dx| or 8
    return mk * mk;
}

// ---------------- Kernel A: fw nibble plane + bit-packed combined mask ----------------
__global__ __launch_bounds__(256) void fw_kernel(
    const float* __restrict__ target, uint16_t* __restrict__ fwnib,
    uint32_t* __restrict__ mask)
{
    __shared__ uint8_t nib[256];
    const int t = threadIdx.x;
    const int i = blockIdx.x * 256 + t;   // quad index, grid sized exactly
    const float4* t4 = (const float4*)target;
    float4 a = t4[i];
    float4 b = t4[(NPIX/4) + i];
    float4 c = t4[2*(NPIX/4) + i];
    float4 d = t4[3*(NPIX/4) + i];
    float4 e = t4[4*(NPIX/4) + i];
    uint32_t f0 = (uint32_t)(a.x + b.x + c.x + d.x + e.x);
    uint32_t f1 = (uint32_t)(a.y + b.y + c.y + d.y + e.y);
    uint32_t f2 = (uint32_t)(a.z + b.z + c.z + d.z + e.z);
    uint32_t f3 = (uint32_t)(a.w + b.w + c.w + d.w + e.w);
    fwnib[i] = (uint16_t)(f0 | (f1 << 4) | (f2 << 8) | (f3 << 12));   // 2 MB plane
    nib[t] = (uint8_t)((f0 ? 1u : 0u) | (f1 ? 2u : 0u) | (f2 ? 4u : 0u) | (f3 ? 8u : 0u));
    __syncthreads();
    if (t < 32) {
        const uint8_t* p = nib + t * 8;
        uint32_t w = 0;
        #pragma unroll
        for (int k = 0; k < 8; ++k) w |= (uint32_t)p[k] << (4 * k);
        mask[blockIdx.x * 32 + t] = w;   // 1024 consecutive pixels per block = 32 words
    }
}

// ---------------- Kernel B: contour -> byte code, per-block min/max ----------------
// R13 diagnosis: 7us, VALU-bound (69%), 1.4M LDS conflict cycles from lutm2 LUT.
// Fix: word-parallel fast path for d2<=2 (resolves ~99% px: combined ~ Bern(0.56)
// iid), exact ALU-gadget cleanup for the rest. No data-dependent LDS LUT.
// Code byte = ((enc-1)<<3)|fw, enc = mind2 (<=32) or 26 ("none"). Bit-exact vs r12.
__global__ __launch_bounds__(256) void contour_kernel(
    const uint16_t* __restrict__ fwnib, const uint32_t* __restrict__ mask,
    const float* __restrict__ dk,
    uint8_t* __restrict__ wcode, float* __restrict__ pmin, float* __restrict__ pmax)
{
    __shared__ uint32_t maskw[TSY + 8][4];  // 40 halo rows x 128 bits (gx0-32..gx0+95)
    __shared__ float    inv_ext[65];        // d^2 -> 1/dist, 0 if unachievable/none(64)
    __shared__ float    redmn[4], redmx[4];

    const int t   = threadIdx.x;
    const int gx0 = blockIdx.x * TSX;
    const int gy0 = blockIdx.y * TSY;
    const int rl  = t >> 3;                 // tile row 0..31
    const int xg  = t & 7;                  // 8-px group in row
    const int gy  = gy0 + rl;
    const int gxb = gx0 + 8 * xg;

    // staging: halo words + own fw dword issued early
    const int w0 = gx0 >> 5;
    if (t < (TSY + 8) * 4) {                // 160 halo words, one per thread
        int hr = t >> 2, wc = t & 3;
        int hgy = gy0 - 4 + hr; hgy = min(max(hgy, 0), HH - 1);
        const uint32_t* rowp = mask + hgy * MROW;
        int wi = w0 - 1 + wc;
        uint32_t v;
        if (wi < 0)            v = (rowp[0] & 1u) ? 0xFFFFFFFFu : 0u;        // left clamp
        else if (wi > MROW-1)  v = (rowp[MROW-1] >> 31) ? 0xFFFFFFFFu : 0u;  // right clamp
        else                   v = rowp[wi];
        maskw[hr][wc] = v;
    }
    const uint32_t fwd = *(const uint32_t*)((const uint8_t*)fwnib + gy * (WW/2) + (gxb >> 1));
    if (t < 65) inv_ext[t] = 0.0f;
    __syncthreads();
    if (t < 81) {                           // fill achievable entries from dk
        int iy = t / 9, jx = t - (t / 9) * 9;
        int dy = iy - 4, dx = jx - 4;
        int d2 = dy * dy + dx * dx;
        if (d2 != 0) inv_ext[d2] = 1.0f / (dk[t] / (1.0f + 1e-10f) + 1e-10f);
    }
    __syncthreads();

    // windows: bit i = col gxb-4+i
    const int pos  = 8 * xg + 28;
    const int wsel = pos >> 5;
    const uint32_t sh = (uint32_t)(pos & 31);
    uint32_t wrow[9];
    #pragma unroll
    for (int k = 0; k < 9; ++k) {
        uint64_t v = (((uint64_t)maskw[rl + k][wsel + 1]) << 32) | maskw[rl + k][wsel];
        wrow[k] = (uint32_t)(v >> sh);
    }

    // ---- word-parallel fast path: d2=1 and d2=2 for all 8 pixels at once ----
    // diff-presence over a position set S: C=0 -> OR(bits in S); C=1 -> ~AND(bits)
    const uint32_t C  = (wrow[4] >> 4) & 0xFFu;    // bit j = center bit of pixel j
    const uint32_t or1  = wrow[3] | wrow[5];
    const uint32_t and1 = wrow[3] & wrow[5];
    uint32_t or_ab  = ((wrow[4] >> 3) | (wrow[4] >> 5)) | (or1 >> 4);   // (+-1,0),(0,+-1)
    uint32_t and_ab = ((wrow[4] >> 3) & (wrow[4] >> 5)) & (and1 >> 4);
    uint32_t P1 = ((C & ~and_ab) | (~C & or_ab)) & 0xFFu;
    uint32_t or_c  = (or1 >> 3) | (or1 >> 5);                           // (+-1,+-1)
    uint32_t and_c = (and1 >> 3) & (and1 >> 5);
    uint32_t P2 = (((C & ~and_c) | (~C & or_c)) & 0xFFu) & ~P1;
    uint32_t unres = 0xFFu & ~(P1 | P2);

    // code bytes: interleave fw nibbles into 8 bytes, add (enc-1)<<3 for take2
    uint32_t u0 = fwd & 0x0F0F0F0Fu;          // n0,n2,n4,n6
    uint32_t u1 = (fwd >> 4) & 0x0F0F0F0Fu;   // n1,n3,n5,n7
    uint32_t outb0 = (u0 & 0xFFu) | ((u1 & 0xFFu) << 8)
                   | ((u0 & 0xFF00u) << 8) | ((u1 & 0xFF00u) << 16);
    uint32_t outb1 = ((u0 >> 16) & 0xFFu) | (((u1 >> 16) & 0xFFu) << 8)
                   | (((u0 >> 24) & 0xFFu) << 16) | (((u1 >> 24) & 0xFFu) << 24);
    outb0 |= (((P2 & 0xFu)  * 0x00204081u) & 0x01010101u) << 3;   // enc=2 -> +8/byte
    outb1 |= (((P2 >> 4)    * 0x00204081u) & 0x01010101u) << 3;

    // min/max for resolved pixels (contour = inv_ext[1] or inv_ext[2], scalar)
    const float c1 = inv_ext[1], c2 = inv_ext[2];
    const float FINF = __int_as_float(0x7F800000);
    float lmn = FINF, lmx = 0.0f;
    #pragma unroll
    for (int j = 0; j < 8; ++j) {
        float fwf = (float)((fwd >> (4 * j)) & 0xFu);
        float ctr = ((P1 >> j) & 1u) ? c1 : (((P2 >> j) & 1u) ? c2 : 0.0f);
        float wv = fwf + ctr;
        wv = wv * wv;
        bool u = ((unres >> j) & 1u) != 0u;
        lmn = fminf(lmn, u ? FINF : wv);
        lmx = fmaxf(lmx, u ? 0.0f : wv);
    }

    // ---- exact cleanup for unresolved pixels (~1%; ~1-2 iterations per wave) ----
    uint32_t un = unres;
    while (__any(un != 0u)) {
        if (un) {
            int j = __builtin_ctz(un);
            un &= un - 1u;
            uint32_t craw = (C >> j) & 1u;
            uint32_t cm = 0u - craw;
            uint32_t d2m = m2gadget(((wrow[4] ^ cm) >> j) & 0x1FFu);   // dy=0
            #pragma unroll
            for (int k = 1; k <= 4; ++k) {
                uint32_t sel = craw ? (wrow[4 - k] & wrow[4 + k])
                                    : (wrow[4 - k] | wrow[4 + k]);
                uint32_t x = ((sel ^ cm) >> j) & 0x1FFu;
                d2m = min(d2m, m2gadget(x) + (uint32_t)(k * k));
            }
            float contour = inv_ext[d2m];                // d2m <= 64; 0 for none
            uint32_t enc = (d2m > 32u) ? 26u : d2m;
            uint32_t val = (enc - 1u) << 3;
            if (j < 4) outb0 |= val << (8 * j);
            else       outb1 |= val << (8 * (j - 4));
            float fwf = (float)((fwd >> (4 * j)) & 0xFu);
            float wv = fwf + contour;
            wv = wv * wv;
            lmn = fminf(lmn, wv);
            lmx = fmaxf(lmx, wv);
        }
    }

    uint2 ob; ob.x = outb0; ob.y = outb1;
    *(uint2*)(wcode + gy * WW + gxb) = ob;

    // block reduce -> one plain store pair (same-address atomics = round-2 disaster)
    #pragma unroll
    for (int off = 32; off > 0; off >>= 1) {
        lmn = fminf(lmn, __shfl_xor(lmn, off));
        lmx = fmaxf(lmx, __shfl_xor(lmx, off));
    }
    if ((t & 63) == 0) { redmn[t >> 6] = lmn; redmx[t >> 6] = lmx; }
    __syncthreads();
    if (t == 0) {
        float mn = fminf(fminf(redmn[0], redmn[1]), fminf(redmn[2], redmn[3]));
        float mx = fmaxf(fmaxf(redmx[0], redmx[1]), fmaxf(redmx[2], redmx[3]));
        int bid = blockIdx.y * gridDim.x + blockIdx.x;
        pmin[bid] = mn;
        pmax[bid] = mx;
    }
}

// ---------------- Kernel C: redundant partial-reduce + LUT decode + normalize ----------------
// 2048 blocks x 256 threads, 8 px/thread; w rebuilt bit-exactly from code byte.
__global__ __launch_bounds__(256) void norm_kernel(
    const uint8_t* __restrict__ wcode, const float* __restrict__ dk,
    const float* __restrict__ pmin, const float* __restrict__ pmax,
    float* __restrict__ out)
{
    __shared__ float ct[33];       // d^2 -> 1/dist (0 where none, incl code 26)
    __shared__ float wlut[256];    // code byte -> w value
    __shared__ float smn[4], smx[4];
    const int t = threadIdx.x;

    if (t < 33) ct[t] = 0.0f;
    const float4* pn4 = (const float4*)pmin;
    const float4* px4 = (const float4*)pmax;
    float4 a = pn4[t * 2], b = pn4[t * 2 + 1];
    float4 c = px4[t * 2], d = px4[t * 2 + 1];
    __syncthreads();
    if (t < 81) {
        int iy = t / 9, jx = t - (t / 9) * 9;
        int dy = iy - 4, dx = jx - 4;
        int d2 = dy * dy + dx * dx;
        if (d2 != 0) ct[d2] = 1.0f / (dk[t] / (1.0f + 1e-10f) + 1e-10f);
    }
    __syncthreads();
    {   // decode LUT: identical arithmetic to contour kernel -> bit-exact
        float wv = (float)(t & 7) + ct[(t >> 3) + 1];
        wlut[t] = wv * wv;
    }
    float mn = fminf(fminf(fminf(a.x, a.y), fminf(a.z, a.w)),
                     fminf(fminf(b.x, b.y), fminf(b.z, b.w)));
    float mx = fmaxf(fmaxf(fmaxf(c.x, c.y), fmaxf(c.z, c.w)),
                     fmaxf(fmaxf(d.x, d.y), fmaxf(d.z, d.w)));
    #pragma unroll
    for (int off = 32; off > 0; off >>= 1) {
        mn = fminf(mn, __shfl_xor(mn, off));
        mx = fmaxf(mx, __shfl_xor(mx, off));
    }
    if ((t & 63) == 0) { smn[t >> 6] = mn; smx[t >> 6] = mx; }
    __syncthreads();
    mn = fminf(fminf(smn[0], smn[1]), fminf(smn[2], smn[3]));
    mx = fmaxf(fmaxf(smx[0], smx[1]), fmaxf(smx[2], smx[3]));
    const float rden = 1.0f / (mx - mn + 1e-10f);

    const int i = blockIdx.x * 256 + t;          // 8-px group id
    uint2 cb = ((const uint2*)wcode)[i];
    uint32_t b0 = cb.x, b1 = cb.y;
    float4 o0, o1;
    o0.x = (b0 & 7u)         ? (wlut[b0 & 0xFFu] - mn) * rden         : 0.0f;
    o0.y = ((b0 >> 8) & 7u)  ? (wlut[(b0 >> 8) & 0xFFu] - mn) * rden  : 0.0f;
    o0.z = ((b0 >> 16) & 7u) ? (wlut[(b0 >> 16) & 0xFFu] - mn) * rden : 0.0f;
    o0.w = ((b0 >> 24) & 7u) ? (wlut[b0 >> 24] - mn) * rden           : 0.0f;
    o1.x = (b1 & 7u)         ? (wlut[b1 & 0xFFu] - mn) * rden         : 0.0f;
    o1.y = ((b1 >> 8) & 7u)  ? (wlut[(b1 >> 8) & 0xFFu] - mn) * rden  : 0.0f;
    o1.z = ((b1 >> 16) & 7u) ? (wlut[(b1 >> 16) & 0xFFu] - mn) * rden : 0.0f;
    o1.w = ((b1 >> 24) & 7u) ? (wlut[b1 >> 24] - mn) * rden           : 0.0f;
    ((float4*)out)[i * 2]     = o0;
    ((float4*)out)[i * 2 + 1] = o1;
}

extern "C" void kernel_launch(void* const* d_in, const int* in_sizes, int n_in,
                              void* d_out, int out_size, void* d_ws, size_t ws_size,
                              hipStream_t stream)
{
    const float* target = (const float*)d_in[0];
    const float* dk     = (const float*)d_in[1];
    float* out = (float*)d_out;

    uint8_t* wsb = (uint8_t*)d_ws;
    uint16_t* fwnib = (uint16_t*)wsb;                        // 2 MB fw nibble plane
    uint8_t*  wcode = wsb + NPIX/2;                          // 4 MB u8 code plane
    uint32_t* mask  = (uint32_t*)(wsb + NPIX/2 + NPIX);      // 512 KB packed mask
    float*    pmin  = (float*)(wsb + NPIX/2 + NPIX + NPIX/8);// 8 KB partial mins
    float*    pmax  = pmin + NBLK;                           // 8 KB partial maxs

    fw_kernel<<<NPIX / 4 / 256, 256, 0, stream>>>(target, fwnib, mask);

    dim3 gridB(WW / TSX, HH / TSY);
    contour_kernel<<<gridB, 256, 0, stream>>>(fwnib, mask, dk, wcode, pmin, pmax);

    norm_kernel<<<NPIX / 8 / 256, 256, 0, stream>>>(wcode, dk, pmin, pmax, out);
}